// Round 2
// baseline (294.445 us; speedup 1.0000x reference)
//
#include <hip/hip_runtime.h>

#define NTAG 32
#define START 30
#define STOP 31
#define LOG2E 1.44269504088896340736f
#define LN2 0.69314718055994530942f
#define PF 8  // prefetch distance (ring size)

__device__ __forceinline__ float fexp2(float x) {
#if __has_builtin(__builtin_amdgcn_exp2f)
    return __builtin_amdgcn_exp2f(x);   // v_exp_f32: 2^x
#else
    return exp2f(x);
#endif
}
__device__ __forceinline__ float flog2(float x) {
#if __has_builtin(__builtin_amdgcn_logf)
    return __builtin_amdgcn_logf(x);    // v_log_f32: log2(x)
#else
    return log2f(x);
#endif
}

// One wave per batch element; lanes 0..31 active, lane j owns tag j.
// Block = 256 threads = 4 waves = 4 batches. Grid = B/4.
__global__ __launch_bounds__(256, 1) void crf_nll_kernel(
    const float* __restrict__ feats,   // B x L x 32
    const float* __restrict__ trans,   // 32 x 32
    const int*   __restrict__ tags,    // B x L
    const int*   __restrict__ wsl,     // B
    float* __restrict__ out, int B, int L)
{
    __shared__ float strans[NTAG * NTAG];
    // stage raw transitions into LDS (all 256 threads)
    for (int i = threadIdx.x; i < NTAG * NTAG; i += 256) strans[i] = trans[i];
    __syncthreads();

    const int wave = threadIdx.x >> 6;
    const int lane = threadIdx.x & 63;
    int b = blockIdx.x * 4 + wave;
    b = __builtin_amdgcn_readfirstlane(b);
    if (lane >= 32 || b >= B) return;
    const int j = lane;

    // per-lane column of exp2(trans * log2e): ET2[i] = 2^(trans[i][j]*log2e)
    float ET2[NTAG];
#pragma unroll
    for (int i = 0; i < NTAG; ++i)
        ET2[i] = fexp2(strans[i * NTAG + j] * LOG2E);
    const float tS2 = strans[j * NTAG + STOP] * LOG2E;  // trans[j,STOP]*log2e

    const int n = wsl[b];
    const float* __restrict__ frow = feats + (size_t)b * L * NTAG;
    const int*   __restrict__ trow = tags  + (size_t)b * L;

    // ---- init (t = 0) ----
    const float feat0 = frow[j];
    const int tag0 = trow[0];
    // invariant: alpha2_j (log2-domain alpha) == u2h_j - l2mx + M2
    float u2h = (strans[START * NTAG + j] + feat0) * LOG2E;
    float l2mx = 0.f, M2 = 0.f;
    // gold: begin term = trans[START, tag0] + feats[b,0,tag0]
    float gacc = (j == tag0) ? (strans[START * NTAG + j] + feat0) : 0.f;
    int tagprev = tag0;

    // ---- prefetch ring ----
    float fpf[PF];
    int   tpf[PF];
#pragma unroll
    for (int d = 0; d < PF; ++d) {
        int t = 1 + d;
        int tc = (t < L - 1) ? t : (L - 1);
        fpf[d] = frow[tc * NTAG + j];
        tpf[d] = trow[tc];
    }

    // ---- serial scan: t = 1 .. n-1 ----
    for (int t = 1; t < n; ++t) {
        const int d = (t - 1) & (PF - 1);
        const float fraw = fpf[d];
        const int   tg   = tpf[d];
        // issue prefetch for t+PF
        {
            int tn = t + PF;
            int tc = (tn < L - 1) ? tn : (L - 1);
            fpf[d] = frow[tc * NTAG + j];
            tpf[d] = trow[tc];
        }

        // e_i = 2^(u_i - l2mx_prev)   (lag-1 renorm keeps args bounded)
        const float e = fexp2(u2h - l2mx);

        // broadcast e via readlane (SGPR) + FMA with SGPR operand; max off-chain
        float acc0 = 0.f, acc1 = 0.f, acc2 = 0.f, acc3 = 0.f;
        unsigned mxu = 0u;
#pragma unroll
        for (int i = 0; i < NTAG; ++i) {
            int eu = __builtin_amdgcn_readlane(__float_as_int(e), i);
            unsigned euu = (unsigned)eu;
            mxu = (euu > mxu) ? euu : mxu;   // positive floats order as uints
            float ef = __int_as_float(eu);
            if ((i & 3) == 0)      acc0 = fmaf(ef, ET2[i], acc0);
            else if ((i & 3) == 1) acc1 = fmaf(ef, ET2[i], acc1);
            else if ((i & 3) == 2) acc2 = fmaf(ef, ET2[i], acc2);
            else                   acc3 = fmaf(ef, ET2[i], acc3);
        }
        const float S = (acc0 + acc1) + (acc2 + acc3);

        // gold: middle term trans[tag_{t-1}, tag_t] + feats[b,t,tag_t]
        const float trc = strans[tagprev * NTAG + j];   // off critical path (LDS)
        gacc += (j == tg) ? (trc + fraw) : 0.f;
        tagprev = tg;

        const float l2S = flog2(S);
        u2h = fmaf(fraw, LOG2E, l2S);          // alpha2_t minus running M2
        const float lm = flog2(__uint_as_float(mxu));  // off chain (used next iter)
        M2 += lm;
        l2mx = lm;
    }

    // gold: end term = trans[tag_last, STOP]
    {
        const float trl = strans[tagprev * NTAG + j];
        gacc += (j == STOP) ? trl : 0.f;
    }

    // forward score: ln2 * (M2 + log2 sum_j 2^(u2_j + tS2_j))
    float v  = u2h - l2mx + tS2;
    float ex = fexp2(v);
#pragma unroll
    for (int k = 1; k < 32; k <<= 1) {
        ex   += __shfl_xor(ex,   k, 32);
        gacc += __shfl_xor(gacc, k, 32);
    }
    if (j == 0) {
        const float fs = LN2 * (M2 + flog2(ex));
        atomicAdd(out, fs - gacc);
    }
}

extern "C" void kernel_launch(void* const* d_in, const int* in_sizes, int n_in,
                              void* d_out, int out_size, void* d_ws, size_t ws_size,
                              hipStream_t stream) {
    const float* feats = (const float*)d_in[0];
    const float* trans = (const float*)d_in[1];
    const int*   tags  = (const int*)d_in[2];
    const int*   wsl   = (const int*)d_in[3];
    float* out = (float*)d_out;

    const int B = in_sizes[3];              // word_seq_lens: (B,)
    const int L = in_sizes[2] / B;          // tags: (B, L)

    (void)hipMemsetAsync(out, 0, sizeof(float), stream);
    const int grid = (B + 3) / 4;
    crf_nll_kernel<<<grid, 256, 0, stream>>>(feats, trans, tags, wsl, out, B, L);
}

// Round 3
// 218.331 us; speedup vs baseline: 1.3486x; 1.3486x over previous
//
#include <hip/hip_runtime.h>

#define NTAG 32
#define START 30
#define STOP 31
#define LOG2E 1.44269504088896340736f
#define LN2 0.69314718055994530942f
#define PF 8  // prefetch distance == unroll factor (ring slots resolved at compile time)

__device__ __forceinline__ float fexp2(float x) {
#if __has_builtin(__builtin_amdgcn_exp2f)
    return __builtin_amdgcn_exp2f(x);   // v_exp_f32: 2^x
#else
    return exp2f(x);
#endif
}
__device__ __forceinline__ float flog2(float x) {
#if __has_builtin(__builtin_amdgcn_logf)
    return __builtin_amdgcn_logf(x);    // v_log_f32: log2(x)
#else
    return log2f(x);
#endif
}

// One wave per batch element; lanes 0..31 active, lane j owns tag j.
// Block = 256 threads = 4 waves = 4 batches. Grid = B/4.
__global__ __launch_bounds__(256, 1) void crf_nll_kernel(
    const float* __restrict__ feats,   // B x L x 32
    const float* __restrict__ trans,   // 32 x 32
    const int*   __restrict__ tags,    // B x L
    const int*   __restrict__ wsl,     // B
    float* __restrict__ out, int B, int L)
{
    __shared__ float strans[NTAG * NTAG];
    for (int i = threadIdx.x; i < NTAG * NTAG; i += 256) strans[i] = trans[i];
    __syncthreads();

    const int wave = threadIdx.x >> 6;
    const int lane = threadIdx.x & 63;
    int b = blockIdx.x * 4 + wave;
    b = __builtin_amdgcn_readfirstlane(b);
    if (lane >= 32 || b >= B) return;
    const int j = lane;

    // per-lane column of exp2(trans * log2e): ET2[i] = 2^(trans[i][j]*log2e)
    // Unrolled constant indexing only -> stays in VGPRs.
    float ET2[NTAG];
#pragma unroll
    for (int i = 0; i < NTAG; ++i)
        ET2[i] = fexp2(strans[i * NTAG + j] * LOG2E);
    const float tS2 = strans[j * NTAG + STOP] * LOG2E;

    const int n = wsl[b];
    const float* __restrict__ frow = feats + (size_t)b * L * NTAG;
    const int*   __restrict__ trow = tags  + (size_t)b * L;

    // ---- init (t = 0) ----
    const float feat0 = frow[j];
    const int tag0 = trow[0];
    // invariant: alpha2_j (log2-domain alpha) == u2h_j - l2mx + M2
    float u2h = (strans[START * NTAG + j] + feat0) * LOG2E;
    float l2mx = 0.f, M2 = 0.f;
    float gacc = (j == tag0) ? (strans[START * NTAG + j] + feat0) : 0.f;
    int tagprev = tag0;

    // ---- prefetch ring (constant indices only) ----
    float fpf[PF];
    int   tpf[PF];
#pragma unroll
    for (int d = 0; d < PF; ++d) {
        int t = 1 + d;
        int tc = (t < L - 1) ? t : (L - 1);
        fpf[d] = frow[tc * NTAG + j];
        tpf[d] = trow[tc];
    }

    // one scan step; slot index is always a compile-time constant at call sites
    auto step_body = [&](float fraw, int tg) {
        // e_i = 2^(u_i - l2mx_prev)   (lag-1 renorm keeps args bounded)
        const float e = fexp2(u2h - l2mx);
        float acc0 = 0.f, acc1 = 0.f, acc2 = 0.f, acc3 = 0.f;
        unsigned mxu = 0u;
#pragma unroll
        for (int i = 0; i < NTAG; ++i) {
            int eu = __builtin_amdgcn_readlane(__float_as_int(e), i);
            unsigned euu = (unsigned)eu;
            mxu = (euu > mxu) ? euu : mxu;   // positive floats order as uints (SALU)
            float ef = __int_as_float(eu);
            if ((i & 3) == 0)      acc0 = fmaf(ef, ET2[i], acc0);
            else if ((i & 3) == 1) acc1 = fmaf(ef, ET2[i], acc1);
            else if ((i & 3) == 2) acc2 = fmaf(ef, ET2[i], acc2);
            else                   acc3 = fmaf(ef, ET2[i], acc3);
        }
        const float S = (acc0 + acc1) + (acc2 + acc3);

        // gold: middle term trans[tag_{t-1}, tag_t] + feats[b,t,tag_t] (off chain)
        const float trc = strans[tagprev * NTAG + j];
        gacc += (j == tg) ? (trc + fraw) : 0.f;
        tagprev = tg;

        const float l2S = flog2(S);
        u2h = fmaf(fraw, LOG2E, l2S);
        const float lm = flog2(__uint_as_float(mxu));  // off chain (used next iter)
        M2 += lm;
        l2mx = lm;
    };

    // ---- serial scan: t = 1 .. n-1, unrolled by PF so ring stays in VGPRs ----
    int t = 1;
    for (; t + PF <= n; t += PF) {
#pragma unroll
        for (int u = 0; u < PF; ++u) {
            const float fraw = fpf[u];
            const int   tg   = tpf[u];
            // prefetch (t+u)+PF into the same slot
            int tn_ = t + u + PF;
            int tc = (tn_ < L - 1) ? tn_ : (L - 1);
            fpf[u] = frow[tc * NTAG + j];
            tpf[u] = trow[tc];
            step_body(fraw, tg);
        }
    }
    // epilogue: remaining (n - t) in [0, PF) steps; slot for time tt is tt - t
#pragma unroll
    for (int u = 0; u < PF; ++u) {
        if (t + u < n) {
            step_body(fpf[u], tpf[u]);
        }
    }

    // gold: end term = trans[tag_last, STOP]
    {
        const float trl = strans[tagprev * NTAG + j];
        gacc += (j == STOP) ? trl : 0.f;
    }

    // forward score: ln2 * (M2 + log2 sum_j 2^(u2_j + tS2_j))
    float v  = u2h - l2mx + tS2;
    float ex = fexp2(v);
#pragma unroll
    for (int k = 1; k < 32; k <<= 1) {
        ex   += __shfl_xor(ex,   k, 32);
        gacc += __shfl_xor(gacc, k, 32);
    }
    if (j == 0) {
        const float fs = LN2 * (M2 + flog2(ex));
        atomicAdd(out, fs - gacc);
    }
}

extern "C" void kernel_launch(void* const* d_in, const int* in_sizes, int n_in,
                              void* d_out, int out_size, void* d_ws, size_t ws_size,
                              hipStream_t stream) {
    const float* feats = (const float*)d_in[0];
    const float* trans = (const float*)d_in[1];
    const int*   tags  = (const int*)d_in[2];
    const int*   wsl   = (const int*)d_in[3];
    float* out = (float*)d_out;

    const int B = in_sizes[3];              // word_seq_lens: (B,)
    const int L = in_sizes[2] / B;          // tags: (B, L)

    (void)hipMemsetAsync(out, 0, sizeof(float), stream);
    const int grid = (B + 3) / 4;
    crf_nll_kernel<<<grid, 256, 0, stream>>>(feats, trans, tags, wsl, out, B, L);
}